// Round 2
// baseline (7573.845 us; speedup 1.0000x reference)
//
#include <hip/hip_runtime.h>
#include <hip/hip_bf16.h>

#define B 2
#define CH 8
#define AM 8
#define NH 8
#define F 256
#define W 768
#define DH 32

typedef __hip_bfloat16 bf16;
#define NE ((size_t)B * AM * F * W)   // 3,145,728 ; also == B*CH*F*W since AM==CH

__device__ __forceinline__ float cvt(float v) { return v; }
__device__ __forceinline__ float cvt(bf16 v)  { return __bfloat162float(v); }
__device__ __forceinline__ void stv(float* p, float v) { *p = v; }
__device__ __forceinline__ void stv(bf16* p, float v)  { *p = __float2bfloat16(v); }

// ---------------------------------------------------------------------------
// Input-dtype probe. If the true dtype is fp32, bf16 slots at EVEN indices are
// the low mantissa halves of floats -> random exponent bits -> mostly outside
// a sane magnitude range. If true bf16, they are N(0,1) samples -> sane.
// flag = 1 -> bf16 inputs/outputs, 0 -> fp32.
// ---------------------------------------------------------------------------
__global__ void detect_kernel(const void* __restrict__ xv, int* __restrict__ flag) {
    __shared__ int cnt[256];
    int tid = threadIdx.x;
    const bf16* xb = (const bf16*)xv;
    float v = fabsf(cvt(xb[2 * tid]));
    cnt[tid] = (v > 1e-3f && v < 1e3f) ? 1 : 0;
    __syncthreads();
    for (int st = 128; st > 0; st >>= 1) {
        if (tid < st) cnt[tid] += cnt[tid + st];
        __syncthreads();
    }
    if (tid == 0) flag[0] = (cnt[0] >= 128) ? 1 : 0;
}

// ---------------------------------------------------------------------------
// Fused conv3x3(+bias) -> positionwise linear -> heads layout -> optional rope.
// One block per (b, am, w); thread g = conv feature f, then output feature g.
// out: (B, AM, NH, W, DH) fp32
// ---------------------------------------------------------------------------
template <typename T>
__device__ __forceinline__ void convpw_body(const T* __restrict__ x, const T* __restrict__ cw,
                                            const T* __restrict__ cb, const T* __restrict__ pw,
                                            float* __restrict__ out, int do_rope,
                                            float* ycol) {
    int blk = blockIdx.x;
    int w = blk % W; int t = blk / W;
    int am = t % AM; int b = t / AM;
    int g = threadIdx.x;

    // conv output at (b, am, f=g, w)
    float acc = cvt(cb[am]);
    for (int c = 0; c < CH; c++) {
        const T* xp = x + ((size_t)(b * CH + c) * F) * W;
        const T* wp = cw + (size_t)(am * CH + c) * 9;
        #pragma unroll
        for (int kh = 0; kh < 3; kh++) {
            int ff = g + kh - 1;
            if (ff < 0 || ff >= F) continue;
            #pragma unroll
            for (int kw = 0; kw < 3; kw++) {
                int ww = w + kw - 1;
                if (ww < 0 || ww >= W) continue;
                acc += cvt(xp[(size_t)ff * W + ww]) * cvt(wp[kh * 3 + kw]);
            }
        }
    }
    ycol[g] = acc;
    __syncthreads();

    const T* wp = pw + ((size_t)am * F + g) * F;
    float s = 0.f;
    for (int f = 0; f < F; f++) s += cvt(wp[f]) * ycol[f];

    float val = s;
    if (do_rope) {
        int dd = g & (DH - 1);
        int i = dd >> 1;                               // pair index 0..15
        float inv = powf(10000.0f, -(float)(2 * i) / (float)DH);
        float ang = (float)w * inv;
        float cs = cosf(ang), sn = sinf(ang);
        float partner = __shfl_xor(s, 1);              // g <-> g^1, same wave
        val = (dd & 1) ? (s * cs + partner * sn)       // odd:  x_o*c + x_e*s
                       : (s * cs - partner * sn);      // even: x_e*c - x_o*s
    }
    int h = g >> 5, d = g & 31;
    out[(((size_t)(b * AM + am) * NH + h) * W + w) * DH + d] = val;
}

__global__ void convpw_kernel(const void* x, const void* cw, const void* cb, const void* pw,
                              float* out, int do_rope, const int* __restrict__ flagp) {
    __shared__ float ycol[F];
    if (*flagp)
        convpw_body<bf16>((const bf16*)x, (const bf16*)cw, (const bf16*)cb, (const bf16*)pw,
                          out, do_rope, ycol);
    else
        convpw_body<float>((const float*)x, (const float*)cw, (const float*)cb, (const float*)pw,
                           out, do_rope, ycol);
}

// ---------------------------------------------------------------------------
// Attention. One block (256 thr) per (b, am, nh, qw) row: scores (768) +
// prev_qk, qk store, softmax, P@V (32).
// ---------------------------------------------------------------------------
template <typename T>
__device__ __forceinline__ void attn_body(const float* __restrict__ q, const float* __restrict__ k,
                                          const float* __restrict__ v, const T* __restrict__ prev,
                                          T* __restrict__ qk_out, float* __restrict__ a,
                                          float* qrow, float* s, float* red, float* part) {
    int blk = blockIdx.x;
    int qw = blk % W; int mat = blk / W;
    int tid = threadIdx.x;
    const float scale = 0.0625f;          // 1/sqrt(256)

    const float* kb = k + (size_t)mat * W * DH;
    const float* vb = v + (size_t)mat * W * DH;
    if (tid < DH) qrow[tid] = q[(size_t)mat * W * DH + (size_t)qw * DH + tid];
    __syncthreads();

    size_t qkrow = ((size_t)mat * W + qw) * (size_t)W;

    float lmax = -1e30f;
    #pragma unroll
    for (int j = 0; j < 3; j++) {
        int kk = tid + j * 256;
        const float* kp = kb + (size_t)kk * DH;
        float acc = 0.f;
        #pragma unroll
        for (int d = 0; d < DH; d++) acc += qrow[d] * kp[d];
        float sv = acc * scale + cvt(prev[qkrow + kk]);
        s[kk] = sv;
        stv(&qk_out[qkrow + kk], sv);
        lmax = fmaxf(lmax, sv);
    }
    red[tid] = lmax; __syncthreads();
    for (int st = 128; st > 0; st >>= 1) {
        if (tid < st) red[tid] = fmaxf(red[tid], red[tid + st]);
        __syncthreads();
    }
    float m = red[0];
    __syncthreads();

    float lsum = 0.f;
    #pragma unroll
    for (int j = 0; j < 3; j++) {
        int kk = tid + j * 256;
        float p = __expf(s[kk] - m);
        s[kk] = p;
        lsum += p;
    }
    red[tid] = lsum; __syncthreads();
    for (int st = 128; st > 0; st >>= 1) {
        if (tid < st) red[tid] += red[tid + st];
        __syncthreads();
    }
    float denom = red[0];
    __syncthreads();

    int g = tid >> 5, d = tid & 31;
    float acc = 0.f;
    for (int j = 0; j < 96; j++) {
        int kk = g * 96 + j;
        acc += s[kk] * vb[(size_t)kk * DH + d];
    }
    part[g * DH + d] = acc;
    __syncthreads();
    if (tid < DH) {
        float sum = 0.f;
        #pragma unroll
        for (int gg = 0; gg < 8; gg++) sum += part[gg * DH + tid];
        a[(size_t)mat * W * DH + (size_t)qw * DH + tid] = sum / denom;
    }
}

__global__ void attn_kernel(const float* q, const float* k, const float* v,
                            const void* prev, void* d_out, float* a,
                            const int* __restrict__ flagp) {
    __shared__ float qrow[DH];
    __shared__ float s[W];
    __shared__ float red[256];
    __shared__ float part[8 * DH];
    if (*flagp) {
        bf16* qk_out = (bf16*)d_out + NE;
        attn_body<bf16>(q, k, v, (const bf16*)prev, qk_out, a, qrow, s, red, part);
    } else {
        float* qk_out = (float*)d_out + NE;
        attn_body<float>(q, k, v, (const float*)prev, qk_out, a, qrow, s, red, part);
    }
}

// ---------------------------------------------------------------------------
// Fused o_proj: positionwise over concat(x, a) then depthwise channel mix.
// One block per (b, w); thread g = feature f. col[c][f] staged in LDS.
// ---------------------------------------------------------------------------
template <typename T>
__device__ __forceinline__ void oproj_body(const T* __restrict__ x, const float* __restrict__ a,
                                           const T* __restrict__ o_pw, const T* __restrict__ o_dw,
                                           T* __restrict__ outp, float* col) {
    int blk = blockIdx.x;
    int w = blk % W; int b = blk / W;
    int g = threadIdx.x;

    for (int c = 0; c < CH; c++)
        col[c * F + g] = cvt(x[((size_t)(b * CH + c) * F + g) * W + w]);
    {
        int h = g >> 5, d = g & 31;
        for (int am = 0; am < AM; am++)
            col[(CH + am) * F + g] = a[(((size_t)(b * AM + am) * NH + h) * W + w) * DH + d];
    }
    __syncthreads();

    float accs[16];
    for (int c = 0; c < 16; c++) {
        const T* wp = o_pw + ((size_t)c * F + g) * F;
        float acc = 0.f;
        for (int f = 0; f < F; f++) acc += cvt(wp[f]) * col[c * F + f];
        accs[c] = acc;
    }
    for (int dch = 0; dch < CH; dch++) {
        float o = 0.f;
        #pragma unroll
        for (int c = 0; c < 16; c++) o += accs[c] * cvt(o_dw[dch * 16 + c]);
        stv(&outp[((size_t)(b * CH + dch) * F + g) * W + w], o);
    }
}

__global__ void oproj_kernel(const void* x, const float* a, const void* o_pw,
                             const void* o_dw, void* d_out, const int* __restrict__ flagp) {
    __shared__ float col[16 * F];
    if (*flagp)
        oproj_body<bf16>((const bf16*)x, a, (const bf16*)o_pw, (const bf16*)o_dw,
                         (bf16*)d_out, col);
    else
        oproj_body<float>((const float*)x, a, (const float*)o_pw, (const float*)o_dw,
                          (float*)d_out, col);
}

extern "C" void kernel_launch(void* const* d_in, const int* in_sizes, int n_in,
                              void* d_out, int out_size, void* d_ws, size_t ws_size,
                              hipStream_t stream) {
    const void* x     = d_in[0];
    const void* prev  = d_in[1];
    const void* q_cw  = d_in[2];
    const void* q_cb  = d_in[3];
    const void* q_pw  = d_in[4];
    const void* k_cw  = d_in[5];
    const void* k_cb  = d_in[6];
    const void* k_pw  = d_in[7];
    const void* v_cw  = d_in[8];
    const void* v_cb  = d_in[9];
    const void* v_pw  = d_in[10];
    const void* o_pw  = d_in[11];
    const void* o_dw  = d_in[12];

    int*   flag = (int*)d_ws;
    float* base = (float*)d_ws + 64;      // 256 B after flag
    float* q = base;                      // 4*NE fp32 total = 50.3 MB
    float* k = q + NE;
    float* v = k + NE;
    float* a = v + NE;

    detect_kernel<<<1, 256, 0, stream>>>(x, flag);

    int pblk = B * AM * W;
    convpw_kernel<<<pblk, 256, 0, stream>>>(x, q_cw, q_cb, q_pw, q, 1, flag);
    convpw_kernel<<<pblk, 256, 0, stream>>>(x, k_cw, k_cb, k_pw, k, 1, flag);
    convpw_kernel<<<pblk, 256, 0, stream>>>(x, v_cw, v_cb, v_pw, v, 0, flag);

    attn_kernel<<<B * AM * NH * W, 256, 0, stream>>>(q, k, v, prev, d_out, a, flag);

    oproj_kernel<<<B * W, 256, 0, stream>>>(x, a, o_pw, o_dw, d_out, flag);
}